// Round 15
// baseline (70.458 us; speedup 1.0000x reference)
//
#include <hip/hip_runtime.h>

typedef float f4 __attribute__((ext_vector_type(4)));
typedef float f2 __attribute__((ext_vector_type(2)));

#define PAD 68              // LDS row pitch (floats); 68%32=4 spreads banks
#define NBLK 256

// ws float layout:
// [0, 12288)   gram[3][4096]  atomic accumulators (zeroed per call)
// [12288]      uint ticket counter (zeroed per call)

// Barrier that does NOT drain outstanding global loads (prefetch survives):
// LDS ordering via lgkmcnt(0), then raw s_barrier; sched_barrier pins code
// motion so later ds ops can't hoist above the barrier.
__device__ __forceinline__ void lds_barrier() {
    asm volatile("s_waitcnt lgkmcnt(0)" ::: "memory");
    __builtin_amdgcn_s_barrier();
    __builtin_amdgcn_sched_barrier(0);
}

__global__ __launch_bounds__(1024) void fused_all_kernel(
    const float* __restrict__ p1, const float* __restrict__ p2,
    float* __restrict__ gram, unsigned* __restrict__ cnt,
    float* __restrict__ out)
{
    __shared__ float la[2][8 * PAD];   // double-buffered 8-row tiles, input A
    __shared__ float lb[2][8 * PAD];   // and input B
    __shared__ unsigned lastf;
    const int t  = threadIdx.x;
    const int b  = blockIdx.x >> 5;    // batch 0..7
    const int oi = blockIdx.x & 31;    // pooled row strip 0..31

    // --- per-thread pool slot ---
    const int m   = t >> 9;            // input select 0/1
    const int c   = (t >> 3) & 63;     // channel
    const int oj8 = t & 7;             // row within sub (8 lanes = 128B seg)
    const float* src = m ? p2 : p1;
    const long base = (long)((b * 64 + c) * 128 + oi * 4) * 128 + oj8 * 4;
    float* dst0 = m ? lb[0] : la[0];
    float* dst1 = m ? lb[1] : la[1];

    // --- norm-wave assignment: wave w owns row (nm, nr), lane = channel ---
    const int l  = t & 63;
    const int w  = t >> 6;
    const int nm = w >> 3, nr = w & 7;

    // --- gram 2x2 tile (r3-identical) ---
    const int c1 = (t >> 5) * 2;
    const int c2 = (t & 31) * 2;
    f2 aa0 = {}, aa1 = {}, ab0 = {}, ab1 = {}, bb0 = {}, bb1 = {};

    auto issue = [&](int q, f4& R0, f4& R1, f4& R2, f4& R3) {
        const float* s = src + base + q * 32;   // sub q: oj = q*8 + oj8
        R0 = __builtin_nontemporal_load((const f4*)(s));
        R1 = __builtin_nontemporal_load((const f4*)(s + 128));
        R2 = __builtin_nontemporal_load((const f4*)(s + 256));
        R3 = __builtin_nontemporal_load((const f4*)(s + 384));
    };
    auto pool = [&](const f4& R0, const f4& R1, const f4& R2, const f4& R3,
                    float* dst) {
        const f4 v = (R0 + R1) + (R2 + R3);
        dst[oj8 * PAD + c] = ((v[0] + v[1]) + (v[2] + v[3])) * 0.0625f;
    };
    auto normphase = [&](int bi) {     // 16 waves: reduce + rescale in place
        float* rowp = (nm ? lb[bi] : la[bi]) + nr * PAD;
        const float v = rowp[l];
        float ss = v * v;
        ss += __shfl_xor(ss, 1);
        ss += __shfl_xor(ss, 2);
        ss += __shfl_xor(ss, 4);
        ss += __shfl_xor(ss, 8);
        ss += __shfl_xor(ss, 16);
        ss += __shfl_xor(ss, 32);
        rowp[l] = v * (1.0f / fmaxf(sqrtf(ss), 1e-8f));
    };
    auto gramacc = [&](int bi) {
        #pragma unroll
        for (int r = 0; r < 8; ++r) {
            const f2 a1 = *(const f2*)&la[bi][r * PAD + c1];
            const f2 a2 = *(const f2*)&la[bi][r * PAD + c2];
            const f2 b1 = *(const f2*)&lb[bi][r * PAD + c1];
            const f2 b2 = *(const f2*)&lb[bi][r * PAD + c2];
            aa0 += a2 * a1[0];  aa1 += a2 * a1[1];
            ab0 += b2 * a1[0];  ab1 += b2 * a1[1];
            bb0 += b2 * b1[0];  bb1 += b2 * b1[1];
        }
    };

    // ---- software pipeline, depth 2 (r11-identical; best measured) ----
    f4 A0, A1, A2, A3, B0, B1, B2, B3;
    issue(0, A0, A1, A2, A3);
    issue(1, B0, B1, B2, B3);

    pool(A0, A1, A2, A3, dst0);  lds_barrier();
    normphase(0);                lds_barrier();
    issue(2, A0, A1, A2, A3);
    gramacc(0);

    pool(B0, B1, B2, B3, dst1);  lds_barrier();
    normphase(1);                lds_barrier();
    issue(3, B0, B1, B2, B3);
    gramacc(1);

    pool(A0, A1, A2, A3, dst0);  lds_barrier();
    normphase(0);                lds_barrier();
    gramacc(0);

    pool(B0, B1, B2, B3, dst1);  lds_barrier();
    normphase(1);                lds_barrier();
    gramacc(1);

    // ---- accumulate into global gram via device-scope float atomics ----
    {
        float* G0 = gram +           c1 * 64 + c2;
        float* G1 = gram + 4096 +    c1 * 64 + c2;
        float* G2 = gram + 8192 +    c1 * 64 + c2;
        atomicAdd(G0,      aa0[0]); atomicAdd(G0 + 1,  aa0[1]);
        atomicAdd(G0 + 64, aa1[0]); atomicAdd(G0 + 65, aa1[1]);
        atomicAdd(G1,      ab0[0]); atomicAdd(G1 + 1,  ab0[1]);
        atomicAdd(G1 + 64, ab1[0]); atomicAdd(G1 + 65, ab1[1]);
        atomicAdd(G2,      bb0[0]); atomicAdd(G2 + 1,  bb0[1]);
        atomicAdd(G2 + 64, bb1[0]); atomicAdd(G2 + 65, bb1[1]);
    }

    // ---- ticket; last-arriving block reduces the 48 KB gram buffer ----
    __syncthreads();   // full drain: this block's atomics are complete
    if (t == 0) {
        unsigned old = __hip_atomic_fetch_add(cnt, 1u, __ATOMIC_ACQ_REL,
                                              __HIP_MEMORY_SCOPE_AGENT);
        lastf = (old == NBLK - 1) ? 1u : 0u;
    }
    __syncthreads();

    if (lastf) {   // block-uniform
        float vsum = 0.f;
        #pragma unroll
        for (int i = 0; i < 4; ++i) {
            const int e = t * 4 + i;          // entry 0..4095
            const float a  = __hip_atomic_load(&gram[e],
                                __ATOMIC_RELAXED, __HIP_MEMORY_SCOPE_AGENT);
            const float mm = __hip_atomic_load(&gram[4096 + e],
                                __ATOMIC_RELAXED, __HIP_MEMORY_SCOPE_AGENT);
            const float bb = __hip_atomic_load(&gram[8192 + e],
                                __ATOMIC_RELAXED, __HIP_MEMORY_SCOPE_AGENT);
            vsum += fmaf(a, a, fmaf(bb, bb, -2.0f * (mm * mm)));
        }
        float* fr = (float*)la;               // reuse LDS (>= 1024 floats)
        fr[t] = vsum;
        __syncthreads();
        for (int s2 = 512; s2 > 0; s2 >>= 1) {
            if (t < s2) fr[t] += fr[t + s2];
            __syncthreads();
        }
        if (t == 0) out[0] = fr[0] * (1.0f / 67108864.0f);  // / 8192^2
    }
}

extern "C" void kernel_launch(void* const* d_in, const int* in_sizes, int n_in,
                              void* d_out, int out_size, void* d_ws, size_t ws_size,
                              hipStream_t stream)
{
    const float* p1 = (const float*)d_in[0];
    const float* p2 = (const float*)d_in[1];
    float* ws   = (float*)d_ws;
    float* gram = ws;                          // 3*4096 floats
    unsigned* cnt = (unsigned*)(ws + 12288);   // 1

    hipMemsetAsync(ws, 0, (12288 + 1) * sizeof(float), stream);
    fused_all_kernel<<<NBLK, 1024, 0, stream>>>(p1, p2, gram, cnt,
                                                (float*)d_out);
}

// Round 16
// 34.264 us; speedup vs baseline: 2.0564x; 2.0564x over previous
//
#include <hip/hip_runtime.h>

typedef float f4 __attribute__((ext_vector_type(4)));
typedef float f2 __attribute__((ext_vector_type(2)));

#define PAD 68              // LDS row pitch (floats); 68%32=4 spreads banks
#define NPART 256           // gram blocks = partial count
#define PART_STRIDE 12288   // 3 * 64*64 floats per block partial

// ws layout (floats):
// [0, 3145728)      partials [256][3][4096]
// [3145728, +256)   bpart (K2)
// [3146240]         uint counter (K2 ticket; reset by K1 block 0)

// Barrier that does NOT drain outstanding global loads (prefetch survives):
// LDS ordering via lgkmcnt(0), then raw s_barrier; sched_barrier pins code
// motion so later ds ops can't hoist above the barrier.
__device__ __forceinline__ void lds_barrier() {
    asm volatile("s_waitcnt lgkmcnt(0)" ::: "memory");
    __builtin_amdgcn_s_barrier();
    __builtin_amdgcn_sched_barrier(0);
}

__global__ __launch_bounds__(1024) void fused_gram_kernel(
    const float* __restrict__ p1, const float* __restrict__ p2,
    float* __restrict__ partials, unsigned* __restrict__ cnt)
{
    __shared__ float la[2][8 * PAD];   // double-buffered row tiles, input A
    __shared__ float lb[2][8 * PAD];   // and input B
    const int t  = threadIdx.x;
    const int b  = blockIdx.x >> 5;    // batch 0..7
    const int oi = blockIdx.x & 31;    // pooled row strip 0..31

    if (blockIdx.x == 0 && t == 0) *cnt = 0u;   // reset K2 ticket each call

    // --- per-thread pool slot (r11 mapping) ---
    const int m   = t >> 9;            // input select 0/1
    const int c   = (t >> 3) & 63;     // channel
    const int oj8 = t & 7;             // row within sub
    const float* src = m ? p2 : p1;
    const long base = (long)((b * 64 + c) * 128 + oi * 4) * 128 + oj8 * 4;
    float* dst0 = m ? lb[0] : la[0];
    float* dst1 = m ? lb[1] : la[1];

    // --- norm-wave assignment: wave w owns row (nm, nr), lane = channel ---
    const int l  = t & 63;
    const int w  = t >> 6;
    const int nm = w >> 3, nr = w & 7;

    // --- gram 2x2 tile (r3/r11-identical) ---
    const int c1 = (t >> 5) * 2;
    const int c2 = (t & 31) * 2;
    f2 aa0 = {}, aa1 = {}, ab0 = {}, ab1 = {}, bb0 = {}, bb1 = {};

    // sub with R rows starting at pooled row ojs: thread covers local row oj8
    auto issue8 = [&](int ojs, f4& R0, f4& R1, f4& R2, f4& R3) {
        const float* s = src + base + ojs * 4;
        R0 = *(const f4*)(s);
        R1 = *(const f4*)(s + 128);
        R2 = *(const f4*)(s + 256);
        R3 = *(const f4*)(s + 384);
    };
    auto issue4 = [&](int ojs, f4& R0, f4& R1, f4& R2, f4& R3) {
        if (oj8 < 4) {
            const float* s = src + base + ojs * 4;
            R0 = *(const f4*)(s);
            R1 = *(const f4*)(s + 128);
            R2 = *(const f4*)(s + 256);
            R3 = *(const f4*)(s + 384);
        }
    };
    auto pool8 = [&](const f4& R0, const f4& R1, const f4& R2, const f4& R3,
                     float* dst) {
        const f4 v = (R0 + R1) + (R2 + R3);
        dst[oj8 * PAD + c] = ((v[0] + v[1]) + (v[2] + v[3])) * 0.0625f;
    };
    auto pool4 = [&](const f4& R0, const f4& R1, const f4& R2, const f4& R3,
                     float* dst) {
        if (oj8 < 4) {
            const f4 v = (R0 + R1) + (R2 + R3);
            dst[oj8 * PAD + c] = ((v[0] + v[1]) + (v[2] + v[3])) * 0.0625f;
        }
    };
    auto norm = [&](int bi, int R) {   // rows 0..R-1: reduce + rescale
        if (nr < R) {
            float* rowp = (nm ? lb[bi] : la[bi]) + nr * PAD;
            const float v = rowp[l];
            float ss = v * v;
            ss += __shfl_xor(ss, 1);
            ss += __shfl_xor(ss, 2);
            ss += __shfl_xor(ss, 4);
            ss += __shfl_xor(ss, 8);
            ss += __shfl_xor(ss, 16);
            ss += __shfl_xor(ss, 32);
            rowp[l] = v * (1.0f / fmaxf(sqrtf(ss), 1e-8f));
        }
    };
    auto gram4 = [&](int bi) {
        #pragma unroll
        for (int r = 0; r < 4; ++r) {
            const f2 a1 = *(const f2*)&la[bi][r * PAD + c1];
            const f2 a2 = *(const f2*)&la[bi][r * PAD + c2];
            const f2 b1 = *(const f2*)&lb[bi][r * PAD + c1];
            const f2 b2 = *(const f2*)&lb[bi][r * PAD + c2];
            aa0 += a2 * a1[0];  aa1 += a2 * a1[1];
            ab0 += b2 * a1[0];  ab1 += b2 * a1[1];
            bb0 += b2 * b1[0];  bb1 += b2 * b1[1];
        }
    };
    auto gram8 = [&](int bi) {
        #pragma unroll
        for (int r = 0; r < 8; ++r) {
            const f2 a1 = *(const f2*)&la[bi][r * PAD + c1];
            const f2 a2 = *(const f2*)&la[bi][r * PAD + c2];
            const f2 b1 = *(const f2*)&lb[bi][r * PAD + c1];
            const f2 b2 = *(const f2*)&lb[bi][r * PAD + c2];
            aa0 += a2 * a1[0];  aa1 += a2 * a1[1];
            ab0 += b2 * a1[0];  ab1 += b2 * a1[1];
            bb0 += b2 * b1[0];  bb1 += b2 * b1[1];
        }
    };

    // ---- pipeline: subs of 4,4,8,8,8 pooled rows (ojs = 0,4,8,16,24).
    // Small first sub halves the ramp stall; each refill issued immediately
    // after the pool that frees its register set. lds_barrier keeps global
    // loads in flight across phases. Buffer alternation 0,1,0,1,0 keeps
    // >=2 barriers between gram(buf) and the next pool-write of that buf.
    f4 X0, X1, X2, X3, Y0, Y1, Y2, Y3;
    issue4(0,  X0, X1, X2, X3);                  // S0
    issue4(4,  Y0, Y1, Y2, Y3);                  // S1

    pool4(X0, X1, X2, X3, dst0);
    issue8(8,  X0, X1, X2, X3);                  // S2
    lds_barrier();  norm(0, 4);  lds_barrier();  gram4(0);

    pool4(Y0, Y1, Y2, Y3, dst1);
    issue8(16, Y0, Y1, Y2, Y3);                  // S3
    lds_barrier();  norm(1, 4);  lds_barrier();  gram4(1);

    pool8(X0, X1, X2, X3, dst0);
    issue8(24, X0, X1, X2, X3);                  // S4
    lds_barrier();  norm(0, 8);  lds_barrier();  gram8(0);

    pool8(Y0, Y1, Y2, Y3, dst1);
    lds_barrier();  norm(1, 8);  lds_barrier();  gram8(1);

    pool8(X0, X1, X2, X3, dst0);
    lds_barrier();  norm(0, 8);  lds_barrier();  gram8(0);

    // ---- partial store: byte-identical layout to round 3 ----
    float* P = partials + (long)blockIdx.x * PART_STRIDE;
    *(f2*)&P[0 * 4096 + (c1    ) * 64 + c2] = aa0;
    *(f2*)&P[0 * 4096 + (c1 + 1) * 64 + c2] = aa1;
    *(f2*)&P[1 * 4096 + (c1    ) * 64 + c2] = ab0;
    *(f2*)&P[1 * 4096 + (c1 + 1) * 64 + c2] = ab1;
    *(f2*)&P[2 * 4096 + (c1    ) * 64 + c2] = bb0;
    *(f2*)&P[2 * 4096 + (c1 + 1) * 64 + c2] = bb1;
}

// K2: byte-identical to round 3's (best measured): 256 blocks x 256 threads.
__global__ __launch_bounds__(256) void reduce_kernel(
    const float* __restrict__ partials, float* __restrict__ bpart,
    unsigned* __restrict__ cnt, float* __restrict__ out)
{
    __shared__ float red[3][16][17];
    __shared__ float vred[16];
    __shared__ float fr[256];
    __shared__ unsigned last_flag;
    const int t  = threadIdx.x;
    const int el = t & 15;
    const int pc = t >> 4;
    const int e  = blockIdx.x * 16 + el;

    float saa = 0.f, sab = 0.f, sbb = 0.f;
    #pragma unroll 4
    for (int i = 0; i < 16; ++i) {
        const float* P = partials + (long)(pc * 16 + i) * PART_STRIDE;
        saa += P[e];
        sab += P[4096 + e];
        sbb += P[8192 + e];
    }
    red[0][el][pc] = saa; red[1][el][pc] = sab; red[2][el][pc] = sbb;
    __syncthreads();

    if (t < 16) {
        float a = 0.f, mm = 0.f, bv = 0.f;
        #pragma unroll
        for (int p = 0; p < 16; ++p) {
            a  += red[0][t][p];
            mm += red[1][t][p];
            bv += red[2][t][p];
        }
        vred[t] = fmaf(a, a, fmaf(bv, bv, -2.0f * (mm * mm)));
    }
    __syncthreads();

    if (t == 0) {
        float s = 0.f;
        #pragma unroll
        for (int i = 0; i < 16; ++i) s += vred[i];
        __hip_atomic_store(&bpart[blockIdx.x], s, __ATOMIC_RELEASE,
                           __HIP_MEMORY_SCOPE_AGENT);
        unsigned old = __hip_atomic_fetch_add(cnt, 1u, __ATOMIC_ACQ_REL,
                                              __HIP_MEMORY_SCOPE_AGENT);
        last_flag = (old == NPART - 1) ? 1u : 0u;
    }
    __syncthreads();

    if (last_flag) {   // block-uniform
        fr[t] = __hip_atomic_load(&bpart[t], __ATOMIC_ACQUIRE,
                                  __HIP_MEMORY_SCOPE_AGENT);
        __syncthreads();
        for (int s2 = 128; s2 > 0; s2 >>= 1) {
            if (t < s2) fr[t] += fr[t + s2];
            __syncthreads();
        }
        if (t == 0) out[0] = fr[0] * (1.0f / 67108864.0f);  // / 8192^2
    }
}

extern "C" void kernel_launch(void* const* d_in, const int* in_sizes, int n_in,
                              void* d_out, int out_size, void* d_ws, size_t ws_size,
                              hipStream_t stream)
{
    const float* p1 = (const float*)d_in[0];
    const float* p2 = (const float*)d_in[1];
    float* ws       = (float*)d_ws;
    float* partials = ws;                                  // 256*12288
    float* bpart    = ws + (long)NPART * PART_STRIDE;      // 256
    unsigned* cnt   = (unsigned*)(ws + 3146240);           // 1

    fused_gram_kernel<<<NPART, 1024, 0, stream>>>(p1, p2, partials, cnt);
    reduce_kernel   <<<NPART, 256, 0, stream>>>(partials, bpart, cnt, (float*)d_out);
}